// Round 17
// baseline (523.634 us; speedup 1.0000x reference)
//
#include <hip/hip_runtime.h>
#include <hip/hip_bf16.h>
#include <cstddef>
#include <cstdint>

#define NNODES 500000
#define DIM    128
#define NSEG   8192
#define TSTEPS 6

typedef __attribute__((ext_vector_type(8))) short bf16x8;
typedef __attribute__((ext_vector_type(4))) float f32x4;
typedef unsigned short ushort_t;

static __device__ inline ushort_t f2bf_u(float f) {
    __hip_bfloat16 h = __float2bfloat16(f);
    return *reinterpret_cast<ushort_t*>(&h);
}
static __device__ inline float bfu2f(ushort_t u) {
    union { unsigned i; float f; } c; c.i = ((unsigned)u) << 16; return c.f;
}

// ---------------------------------------------------------------------------
// Setup: wconv + seg_bounds folded.
// ---------------------------------------------------------------------------
__global__ __launch_bounds__(256) void setup_k(
    const float* __restrict__ Wih, const float* __restrict__ Whh,
    __hip_bfloat16* __restrict__ wbuf,
    const int* __restrict__ batch, int* __restrict__ seg)
{
    int idx = blockIdx.x * 256 + threadIdx.x;    // 0..196607
    {
        int n = idx / 384, k = idx - n * 384;
        float v = (k < 256) ? Wih[n * 256 + k] : Whh[n * 128 + (k - 256)];
        wbuf[idx] = __float2bfloat16(v);
    }
    if (idx <= NSEG) {
        int lo = 0, hi = NNODES;
        while (lo < hi) {
            int mid = (lo + hi) >> 1;
            if (batch[mid] < idx) lo = mid + 1; else hi = mid;
        }
        seg[idx] = lo;
    }
}

// ---------------------------------------------------------------------------
// gates = Abf @ Wbf^T  (fp32 accumulate). Unchanged from round 15.
// ---------------------------------------------------------------------------
__global__ __launch_bounds__(256) void gemm_mfma_k(
    const __hip_bfloat16* __restrict__ abuf,
    const __hip_bfloat16* __restrict__ wbuf,
    float* __restrict__ gates)
{
    __shared__ char As[128 * 128];
    __shared__ char Bs[64 * 128];
    const int tid  = threadIdx.x;
    const int lane = tid & 63, wave = tid >> 6;
    const int wrow = (wave >> 1) * 64;
    const int wcol = (wave & 1) * 32;
    const int m0 = blockIdx.y * 128;
    const int n0 = blockIdx.x * 64;

    const int ar  = tid >> 1;
    const int acb = (tid & 1) * 64;
    const int br  = tid >> 2;
    const int bcb = (tid & 3) * 32;

    const char* aP = (const char*)(abuf + (size_t)(m0 + ar) * 384) + acb;
    const char* bP = (const char*)(wbuf + (size_t)(n0 + br) * 384) + bcb;

    f32x4 acc[4][2] = {};

    int4 ra[4]; int4 rb2[2];
    #pragma unroll
    for (int c = 0; c < 4; ++c) ra[c]  = *(const int4*)(aP + c * 16);
    #pragma unroll
    for (int c = 0; c < 2; ++c) rb2[c] = *(const int4*)(bP + c * 16);

    char* asw = As + ar * 128;
    char* bsw = Bs + br * 128;
    const int amask = (ar & 7) << 4;
    const int bmask = (br & 7) << 4;

    for (int s = 0; s < 6; ++s) {
        __syncthreads();
        #pragma unroll
        for (int c = 0; c < 4; ++c)
            *(int4*)(asw + ((acb + c * 16) ^ amask)) = ra[c];
        #pragma unroll
        for (int c = 0; c < 2; ++c)
            *(int4*)(bsw + ((bcb + c * 16) ^ bmask)) = rb2[c];
        __syncthreads();

        if (s < 5) {
            const char* aN = aP + (size_t)(s + 1) * 128;
            const char* bN = bP + (size_t)(s + 1) * 128;
            #pragma unroll
            for (int c = 0; c < 4; ++c) ra[c]  = *(const int4*)(aN + c * 16);
            #pragma unroll
            for (int c = 0; c < 2; ++c) rb2[c] = *(const int4*)(bN + c * 16);
        }

        #pragma unroll
        for (int ks = 0; ks < 2; ++ks) {
            const int kb = ks * 64 + ((lane >> 4) << 4);
            bf16x8 af[4], bfr[2];
            #pragma unroll
            for (int rbk = 0; rbk < 4; ++rbk) {
                int r = wrow + rbk * 16 + (lane & 15);
                af[rbk] = *(const bf16x8*)(As + r * 128 + (kb ^ ((r & 7) << 4)));
            }
            #pragma unroll
            for (int cb = 0; cb < 2; ++cb) {
                int n = wcol + cb * 16 + (lane & 15);
                bfr[cb] = *(const bf16x8*)(Bs + n * 128 + (kb ^ ((n & 7) << 4)));
            }
            #pragma unroll
            for (int rbk = 0; rbk < 4; ++rbk)
                #pragma unroll
                for (int cb = 0; cb < 2; ++cb)
                    acc[rbk][cb] = __builtin_amdgcn_mfma_f32_16x16x32_bf16(
                        af[rbk], bfr[cb], acc[rbk][cb], 0, 0, 0);
        }
    }

    const int rowb = (lane >> 4) << 2;
    const int coll = lane & 15;
    #pragma unroll
    for (int rbk = 0; rbk < 4; ++rbk)
        #pragma unroll
        for (int cb = 0; cb < 2; ++cb) {
            int row = m0 + wrow + rbk * 16 + rowb;
            int col = n0 + wcol + cb * 16 + coll;
            float* gp = gates + (size_t)row * 512 + col;
            #pragma unroll
            for (int reg = 0; reg < 4; ++reg)
                gp[(size_t)reg * 512] = acc[rbk][cb][reg];
        }
}

#define REDUCE16(s) do { \
    s += __shfl_xor(s, 1); s += __shfl_xor(s, 2); \
    s += __shfl_xor(s, 4); s += __shfl_xor(s, 8); } while (0)

// ---------------------------------------------------------------------------
// Fused LSTM + flash attention (round-15 body), made IDEMPOTENT via
// cbuf ping-pong (cin read-only, cout write-only) so a second identical
// launch is a no-op numerically -> double-launch measures attn directly.
// ---------------------------------------------------------------------------
__global__ __launch_bounds__(128) void attn_lstm_k(
    const float* __restrict__ x, ushort_t* __restrict__ xbf,
    const int* __restrict__ seg, const float* __restrict__ gates,
    const float* __restrict__ bih, const float* __restrict__ bhh,
    const float* __restrict__ cin, float* __restrict__ cout,
    float* __restrict__ qstar, __hip_bfloat16* __restrict__ abuf,
    int t0, int read_bf, int write_bf)
{
    const int tid  = threadIdx.x;
    const int wv   = tid >> 6, lane = tid & 63;
    const int b    = blockIdx.x;
    const int l16  = lane & 15;
    const int ggrp = (wv << 2) | (lane >> 4);   // 0..7

    __shared__ float hsh[128];
    __shared__ float gm[8], gden[8];
    __shared__ float racc_s[8][128];

    // ---- LSTM prologue: dim d = tid
    {
        const int d = tid;
        float gi, gf, gg, go;
        if (t0) {
            gi = bih[d]       + bhh[d];
            gf = bih[128 + d] + bhh[128 + d];
            gg = bih[256 + d] + bhh[256 + d];
            go = bih[384 + d] + bhh[384 + d];
        } else {
            const float* g = gates + (size_t)b * 512;
            gi = g[d]       + bih[d]       + bhh[d];
            gf = g[128 + d] + bih[128 + d] + bhh[128 + d];
            gg = g[256 + d] + bih[256 + d] + bhh[256 + d];
            go = g[384 + d] + bih[384 + d] + bhh[384 + d];
        }
        float iv = 1.f / (1.f + expf(-gi));
        float fv = 1.f / (1.f + expf(-gf));
        float gv = tanhf(gg);
        float ov = 1.f / (1.f + expf(-go));
        float cp = t0 ? 0.f : cin[(size_t)b * 128 + d];
        float c  = fv * cp + iv * gv;
        float h  = ov * tanhf(c);
        cout[(size_t)b * 128 + d] = c;
        qstar[(size_t)b * 256 + d] = h;
        __hip_bfloat16 hb = __float2bfloat16(h);
        abuf[(size_t)b * 384 + d] = hb;
        abuf[(size_t)b * 384 + 256 + d] = hb;
        hsh[d] = h;
    }
    __syncthreads();

    const int ns = seg[b], ne = seg[b + 1];
    if (ns >= ne) {
        qstar[(size_t)b * 256 + DIM + tid] = 0.f;
        abuf[(size_t)b * 384 + 128 + tid] = __float2bfloat16(0.f);
        return;
    }

    // lane's 8 dims: [8*l16, 8*l16+8)
    float hreg[8];
    #pragma unroll
    for (int i = 0; i < 8; ++i) hreg[i] = hsh[8 * l16 + i];

    float m = -INFINITY, den = 0.f;
    float racc[8] = {};

    if (read_bf) {
        int j = ns + ggrp;
        if (j < ne) {
            const size_t off = 8 * l16;
            int4 v0, v1, v2, v3;
            v0 = *(const int4*)(xbf + (size_t)j * DIM + off);
            v1 = *(const int4*)(xbf + (size_t)(j + 8  < ne ? j + 8  : j) * DIM + off);
            v2 = *(const int4*)(xbf + (size_t)(j + 16 < ne ? j + 16 : j) * DIM + off);
            v3 = *(const int4*)(xbf + (size_t)(j + 24 < ne ? j + 24 : j) * DIM + off);
            while (true) {
                const int jn = j + 32;
                const bool more = (jn < ne);
                int4 n0v, n1v, n2v, n3v;
                if (more) {
                    n0v = *(const int4*)(xbf + (size_t)jn * DIM + off);
                    n1v = *(const int4*)(xbf + (size_t)(jn + 8  < ne ? jn + 8  : jn) * DIM + off);
                    n2v = *(const int4*)(xbf + (size_t)(jn + 16 < ne ? jn + 16 : jn) * DIM + off);
                    n3v = *(const int4*)(xbf + (size_t)(jn + 24 < ne ? jn + 24 : jn) * DIM + off);
                }
                float x0[8], x1[8], x2[8], x3[8];
                {
                    const ushort_t* u0 = (const ushort_t*)&v0;
                    const ushort_t* u1 = (const ushort_t*)&v1;
                    const ushort_t* u2 = (const ushort_t*)&v2;
                    const ushort_t* u3 = (const ushort_t*)&v3;
                    #pragma unroll
                    for (int i = 0; i < 8; ++i) {
                        x0[i] = bfu2f(u0[i]); x1[i] = bfu2f(u1[i]);
                        x2[i] = bfu2f(u2[i]); x3[i] = bfu2f(u3[i]);
                    }
                }
                float s0 = 0.f, s1 = 0.f, s2 = 0.f, s3 = 0.f;
                #pragma unroll
                for (int i = 0; i < 8; ++i) {
                    s0 = fmaf(x0[i], hreg[i], s0);
                    s1 = fmaf(x1[i], hreg[i], s1);
                    s2 = fmaf(x2[i], hreg[i], s2);
                    s3 = fmaf(x3[i], hreg[i], s3);
                }
                REDUCE16(s0); REDUCE16(s1); REDUCE16(s2); REDUCE16(s3);
                if (j + 8  >= ne) s1 = -INFINITY;
                if (j + 16 >= ne) s2 = -INFINITY;
                if (j + 24 >= ne) s3 = -INFINITY;
                const float mn = fmaxf(fmaxf(m, s0), fmaxf(fmaxf(s1, s2), s3));
                const float sc = expf(m - mn);
                const float w0 = expf(s0 - mn), w1 = expf(s1 - mn);
                const float w2 = expf(s2 - mn), w3 = expf(s3 - mn);
                den = den * sc + ((w0 + w1) + (w2 + w3));
                #pragma unroll
                for (int i = 0; i < 8; ++i) {
                    float tacc = w0 * x0[i];
                    tacc = fmaf(w1, x1[i], tacc);
                    tacc = fmaf(w2, x2[i], tacc);
                    tacc = fmaf(w3, x3[i], tacc);
                    racc[i] = fmaf(racc[i], sc, tacc);
                }
                m = mn;
                if (!more) break;
                j = jn;
                v0 = n0v; v1 = n1v; v2 = n2v; v3 = n3v;
            }
        }
    } else {
        for (int j = ns + ggrp; j < ne; j += 32) {
            const int jr[4] = {j, j + 8, j + 16, j + 24};
            float xv[4][8];
            #pragma unroll
            for (int r4 = 0; r4 < 4; ++r4) {
                const int ja = (jr[r4] < ne) ? jr[r4] : j;
                const float4* xp = (const float4*)(x + (size_t)ja * DIM + 8 * l16);
                float4 a = xp[0], bq = xp[1];
                xv[r4][0] = a.x;  xv[r4][1] = a.y;  xv[r4][2] = a.z;  xv[r4][3] = a.w;
                xv[r4][4] = bq.x; xv[r4][5] = bq.y; xv[r4][6] = bq.z; xv[r4][7] = bq.w;
            }
            if (write_bf) {
                #pragma unroll
                for (int r4 = 0; r4 < 4; ++r4) {
                    if (r4 == 0 || jr[r4] < ne) {
                        int4 pk;
                        unsigned* pu = (unsigned*)&pk;
                        #pragma unroll
                        for (int i = 0; i < 4; ++i)
                            pu[i] = (unsigned)f2bf_u(xv[r4][2 * i])
                                  | ((unsigned)f2bf_u(xv[r4][2 * i + 1]) << 16);
                        *(int4*)(xbf + (size_t)jr[r4] * DIM + 8 * l16) = pk;
                    }
                }
            }
            float s0 = 0.f, s1 = 0.f, s2 = 0.f, s3 = 0.f;
            #pragma unroll
            for (int i = 0; i < 8; ++i) {
                s0 = fmaf(xv[0][i], hreg[i], s0);
                s1 = fmaf(xv[1][i], hreg[i], s1);
                s2 = fmaf(xv[2][i], hreg[i], s2);
                s3 = fmaf(xv[3][i], hreg[i], s3);
            }
            REDUCE16(s0); REDUCE16(s1); REDUCE16(s2); REDUCE16(s3);
            if (jr[1] >= ne) s1 = -INFINITY;
            if (jr[2] >= ne) s2 = -INFINITY;
            if (jr[3] >= ne) s3 = -INFINITY;
            const float mn = fmaxf(fmaxf(m, s0), fmaxf(fmaxf(s1, s2), s3));
            const float sc = expf(m - mn);
            const float w0 = expf(s0 - mn), w1 = expf(s1 - mn);
            const float w2 = expf(s2 - mn), w3 = expf(s3 - mn);
            den = den * sc + ((w0 + w1) + (w2 + w3));
            #pragma unroll
            for (int i = 0; i < 8; ++i) {
                float tacc = w0 * xv[0][i];
                tacc = fmaf(w1, xv[1][i], tacc);
                tacc = fmaf(w2, xv[2][i], tacc);
                tacc = fmaf(w3, xv[3][i], tacc);
                racc[i] = fmaf(racc[i], sc, tacc);
            }
            m = mn;
        }
    }

    // ---- merge 8 group states
    if (l16 == 0) { gm[ggrp] = m; gden[ggrp] = den; }
    *(float4*)&racc_s[ggrp][8 * l16]     = make_float4(racc[0], racc[1], racc[2], racc[3]);
    *(float4*)&racc_s[ggrp][8 * l16 + 4] = make_float4(racc[4], racc[5], racc[6], racc[7]);
    __syncthreads();

    {
        float mM = gm[0];
        #pragma unroll
        for (int g = 1; g < 8; ++g) mM = fmaxf(mM, gm[g]);
        float dtot = 0.f, rtot = 0.f;
        #pragma unroll
        for (int g = 0; g < 8; ++g) {
            const float k = expf(gm[g] - mM);   // -inf group -> 0
            dtot = fmaf(k, gden[g], dtot);
            rtot = fmaf(k, racc_s[g][tid], rtot);
        }
        const float rv = rtot / (dtot + 1e-16f);
        qstar[(size_t)b * 256 + DIM + tid] = rv;
        abuf[(size_t)b * 384 + 128 + tid] = __float2bfloat16(rv);
    }
}

// ---------------------------------------------------------------------------
extern "C" void kernel_launch(void* const* d_in, const int* in_sizes, int n_in,
                              void* d_out, int out_size, void* d_ws, size_t ws_size,
                              hipStream_t stream) {
    const float* x     = (const float*)d_in[0];
    const int*   batch = (const int*)d_in[1];
    const float* Wih   = (const float*)d_in[2];
    const float* Whh   = (const float*)d_in[3];
    const float* bih   = (const float*)d_in[4];
    const float* bhh   = (const float*)d_in[5];
    float* out = (float*)d_out;

    // workspace layout (cbuf ping-pong doubles the cbuf region)
    float* cbufA = (float*)d_ws;                            // 8192*128 f32
    float* cbufB = cbufA + (size_t)NSEG * DIM;              // 8192*128 f32
    float* gates = cbufB + (size_t)NSEG * DIM;              // 8192*512 f32
    __hip_bfloat16* abuf = (__hip_bfloat16*)(gates + (size_t)NSEG * 512);  // 8192*384
    __hip_bfloat16* wbuf = abuf + (size_t)NSEG * 384;       // 512*384
    int* seg = (int*)(wbuf + (size_t)512 * 384);
    size_t fixed_bytes = (size_t)((char*)(seg + NSEG + 1) - (char*)d_ws);
    size_t xbf_off = (fixed_bytes + 15) & ~(size_t)15;
    ushort_t* xbf = (ushort_t*)((char*)d_ws + xbf_off);
    size_t need = xbf_off + (size_t)NNODES * DIM * sizeof(ushort_t);
    const int use_xbf = (ws_size >= need) ? 1 : 0;

    setup_k<<<(512 * 384) / 256, 256, 0, stream>>>(Wih, Whh, wbuf, batch, seg);

    float* cpp[2] = {cbufA, cbufB};
    dim3 ggrid(512 / 64, NSEG / 128);   // (8, 64)
    for (int t = 0; t < TSTEPS; ++t) {
        if (t > 0)
            gemm_mfma_k<<<ggrid, 256, 0, stream>>>(abuf, wbuf, gates);
        const int read_bf  = (use_xbf && t > 0) ? 1 : 0;
        const int write_bf = (use_xbf && t == 0) ? 1 : 0;
        const float* cin = cpp[(t + 1) & 1];
        float*       cot = cpp[t & 1];
        const int reps = (t > 0) ? 2 : 1;   // MEASUREMENT: double-launch t>=1
        for (int rep = 0; rep < reps; ++rep)
            attn_lstm_k<<<NSEG, 128, 0, stream>>>(x, xbf, seg, gates, bih, bhh,
                                                  cin, cot, out, abuf,
                                                  (t == 0) ? 1 : 0, read_bf, write_bf);
    }
}

// Round 18
// 349.149 us; speedup vs baseline: 1.4997x; 1.4997x over previous
//
#include <hip/hip_runtime.h>
#include <hip/hip_bf16.h>
#include <cstddef>
#include <cstdint>

#define NNODES 500000
#define DIM    128
#define NSEG   8192
#define TSTEPS 6

typedef __attribute__((ext_vector_type(8))) short bf16x8;
typedef __attribute__((ext_vector_type(4))) float f32x4;
typedef unsigned short ushort_t;

static __device__ inline ushort_t f2bf_u(float f) {
    __hip_bfloat16 h = __float2bfloat16(f);
    return *reinterpret_cast<ushort_t*>(&h);
}
static __device__ inline float bfu2f(ushort_t u) {
    union { unsigned i; float f; } c; c.i = ((unsigned)u) << 16; return c.f;
}

// ---------------------------------------------------------------------------
// Setup: wconv + seg_bounds folded.
// ---------------------------------------------------------------------------
__global__ __launch_bounds__(256) void setup_k(
    const float* __restrict__ Wih, const float* __restrict__ Whh,
    __hip_bfloat16* __restrict__ wbuf,
    const int* __restrict__ batch, int* __restrict__ seg)
{
    int idx = blockIdx.x * 256 + threadIdx.x;    // 0..196607
    {
        int n = idx / 384, k = idx - n * 384;
        float v = (k < 256) ? Wih[n * 256 + k] : Whh[n * 128 + (k - 256)];
        wbuf[idx] = __float2bfloat16(v);
    }
    if (idx <= NSEG) {
        int lo = 0, hi = NNODES;
        while (lo < hi) {
            int mid = (lo + hi) >> 1;
            if (batch[mid] < idx) lo = mid + 1; else hi = mid;
        }
        seg[idx] = lo;
    }
}

// ---------------------------------------------------------------------------
// gates = Abf @ Wbf^T  (fp32 accumulate). BM=128 BN=128 BK=64, 4 waves (2x2),
// grid (4,64): A-panel re-read halved vs BN=64.
// ---------------------------------------------------------------------------
__global__ __launch_bounds__(256) void gemm_mfma_k(
    const __hip_bfloat16* __restrict__ abuf,
    const __hip_bfloat16* __restrict__ wbuf,
    float* __restrict__ gates)
{
    __shared__ char As[128 * 128];
    __shared__ char Bs[128 * 128];
    const int tid  = threadIdx.x;
    const int lane = tid & 63, wave = tid >> 6;
    const int wrow = (wave >> 1) * 64;
    const int wcol = (wave & 1) * 64;
    const int m0 = blockIdx.y * 128;
    const int n0 = blockIdx.x * 128;

    const int ar  = tid >> 1;            // 0..127, 2 threads/row
    const int acb = (tid & 1) * 64;      // byte offset within 128-B row window

    const char* aP = (const char*)(abuf + (size_t)(m0 + ar) * 384) + acb;
    const char* bP = (const char*)(wbuf + (size_t)(n0 + ar) * 384) + acb;

    f32x4 acc[4][4] = {};

    int4 ra[4], rb[4];
    #pragma unroll
    for (int c = 0; c < 4; ++c) { ra[c] = *(const int4*)(aP + c * 16);
                                  rb[c] = *(const int4*)(bP + c * 16); }

    char* asw = As + ar * 128;
    char* bsw = Bs + ar * 128;
    const int amask = (ar & 7) << 4;

    for (int s = 0; s < 6; ++s) {
        __syncthreads();
        #pragma unroll
        for (int c = 0; c < 4; ++c) {
            *(int4*)(asw + ((acb + c * 16) ^ amask)) = ra[c];
            *(int4*)(bsw + ((acb + c * 16) ^ amask)) = rb[c];
        }
        __syncthreads();

        if (s < 5) {
            const char* aN = aP + (size_t)(s + 1) * 128;
            const char* bN = bP + (size_t)(s + 1) * 128;
            #pragma unroll
            for (int c = 0; c < 4; ++c) { ra[c] = *(const int4*)(aN + c * 16);
                                          rb[c] = *(const int4*)(bN + c * 16); }
        }

        #pragma unroll
        for (int ks = 0; ks < 2; ++ks) {
            const int kb = ks * 64 + ((lane >> 4) << 4);
            bf16x8 af[4], bfr[4];
            #pragma unroll
            for (int rbk = 0; rbk < 4; ++rbk) {
                int r = wrow + rbk * 16 + (lane & 15);
                af[rbk] = *(const bf16x8*)(As + r * 128 + (kb ^ ((r & 7) << 4)));
            }
            #pragma unroll
            for (int cb = 0; cb < 4; ++cb) {
                int n = wcol + cb * 16 + (lane & 15);
                bfr[cb] = *(const bf16x8*)(Bs + n * 128 + (kb ^ ((n & 7) << 4)));
            }
            #pragma unroll
            for (int rbk = 0; rbk < 4; ++rbk)
                #pragma unroll
                for (int cb = 0; cb < 4; ++cb)
                    acc[rbk][cb] = __builtin_amdgcn_mfma_f32_16x16x32_bf16(
                        af[rbk], bfr[cb], acc[rbk][cb], 0, 0, 0);
        }
    }

    const int rowb = (lane >> 4) << 2;
    const int coll = lane & 15;
    #pragma unroll
    for (int rbk = 0; rbk < 4; ++rbk)
        #pragma unroll
        for (int cb = 0; cb < 4; ++cb) {
            int row = m0 + wrow + rbk * 16 + rowb;
            int col = n0 + wcol + cb * 16 + coll;
            float* gp = gates + (size_t)row * 512 + col;
            #pragma unroll
            for (int reg = 0; reg < 4; ++reg)
                gp[(size_t)reg * 512] = acc[rbk][cb][reg];
        }
}

#define REDUCE16(s) do { \
    s += __shfl_xor(s, 1); s += __shfl_xor(s, 2); \
    s += __shfl_xor(s, 4); s += __shfl_xor(s, 8); } while (0)

// ---------------------------------------------------------------------------
// Fused LSTM + flash attention, 4-row-batched, depth-2 batch prefetch on
// BOTH paths (bf16 t>=1 and fp32+convert t=0). cbuf ping-pong (idempotent).
// ---------------------------------------------------------------------------
__global__ __launch_bounds__(128) void attn_lstm_k(
    const float* __restrict__ x, ushort_t* __restrict__ xbf,
    const int* __restrict__ seg, const float* __restrict__ gates,
    const float* __restrict__ bih, const float* __restrict__ bhh,
    const float* __restrict__ cin, float* __restrict__ cout,
    float* __restrict__ qstar, __hip_bfloat16* __restrict__ abuf,
    int t0, int read_bf, int write_bf)
{
    const int tid  = threadIdx.x;
    const int wv   = tid >> 6, lane = tid & 63;
    const int b    = blockIdx.x;
    const int l16  = lane & 15;
    const int ggrp = (wv << 2) | (lane >> 4);   // 0..7

    __shared__ float hsh[128];
    __shared__ float gm[8], gden[8];
    __shared__ float racc_s[8][128];

    // ---- LSTM prologue: dim d = tid
    {
        const int d = tid;
        float gi, gf, gg, go;
        if (t0) {
            gi = bih[d]       + bhh[d];
            gf = bih[128 + d] + bhh[128 + d];
            gg = bih[256 + d] + bhh[256 + d];
            go = bih[384 + d] + bhh[384 + d];
        } else {
            const float* g = gates + (size_t)b * 512;
            gi = g[d]       + bih[d]       + bhh[d];
            gf = g[128 + d] + bih[128 + d] + bhh[128 + d];
            gg = g[256 + d] + bih[256 + d] + bhh[256 + d];
            go = g[384 + d] + bih[384 + d] + bhh[384 + d];
        }
        float iv = 1.f / (1.f + expf(-gi));
        float fv = 1.f / (1.f + expf(-gf));
        float gv = tanhf(gg);
        float ov = 1.f / (1.f + expf(-go));
        float cp = t0 ? 0.f : cin[(size_t)b * 128 + d];
        float c  = fv * cp + iv * gv;
        float h  = ov * tanhf(c);
        cout[(size_t)b * 128 + d] = c;
        qstar[(size_t)b * 256 + d] = h;
        __hip_bfloat16 hb = __float2bfloat16(h);
        abuf[(size_t)b * 384 + d] = hb;
        abuf[(size_t)b * 384 + 256 + d] = hb;
        hsh[d] = h;
    }
    __syncthreads();

    const int ns = seg[b], ne = seg[b + 1];
    if (ns >= ne) {
        qstar[(size_t)b * 256 + DIM + tid] = 0.f;
        abuf[(size_t)b * 384 + 128 + tid] = __float2bfloat16(0.f);
        return;
    }

    float hreg[8];
    #pragma unroll
    for (int i = 0; i < 8; ++i) hreg[i] = hsh[8 * l16 + i];

    float m = -INFINITY, den = 0.f;
    float racc[8] = {};

    if (read_bf) {
        int j = ns + ggrp;
        if (j < ne) {
            const size_t off = 8 * l16;
            int4 v0, v1, v2, v3;
            v0 = *(const int4*)(xbf + (size_t)j * DIM + off);
            v1 = *(const int4*)(xbf + (size_t)(j + 8  < ne ? j + 8  : j) * DIM + off);
            v2 = *(const int4*)(xbf + (size_t)(j + 16 < ne ? j + 16 : j) * DIM + off);
            v3 = *(const int4*)(xbf + (size_t)(j + 24 < ne ? j + 24 : j) * DIM + off);
            while (true) {
                const int jn = j + 32;
                const bool more = (jn < ne);
                int4 n0v, n1v, n2v, n3v;
                if (more) {
                    n0v = *(const int4*)(xbf + (size_t)jn * DIM + off);
                    n1v = *(const int4*)(xbf + (size_t)(jn + 8  < ne ? jn + 8  : jn) * DIM + off);
                    n2v = *(const int4*)(xbf + (size_t)(jn + 16 < ne ? jn + 16 : jn) * DIM + off);
                    n3v = *(const int4*)(xbf + (size_t)(jn + 24 < ne ? jn + 24 : jn) * DIM + off);
                }
                float x0[8], x1[8], x2[8], x3[8];
                {
                    const ushort_t* u0 = (const ushort_t*)&v0;
                    const ushort_t* u1 = (const ushort_t*)&v1;
                    const ushort_t* u2 = (const ushort_t*)&v2;
                    const ushort_t* u3 = (const ushort_t*)&v3;
                    #pragma unroll
                    for (int i = 0; i < 8; ++i) {
                        x0[i] = bfu2f(u0[i]); x1[i] = bfu2f(u1[i]);
                        x2[i] = bfu2f(u2[i]); x3[i] = bfu2f(u3[i]);
                    }
                }
                float s0 = 0.f, s1 = 0.f, s2 = 0.f, s3 = 0.f;
                #pragma unroll
                for (int i = 0; i < 8; ++i) {
                    s0 = fmaf(x0[i], hreg[i], s0);
                    s1 = fmaf(x1[i], hreg[i], s1);
                    s2 = fmaf(x2[i], hreg[i], s2);
                    s3 = fmaf(x3[i], hreg[i], s3);
                }
                REDUCE16(s0); REDUCE16(s1); REDUCE16(s2); REDUCE16(s3);
                if (j + 8  >= ne) s1 = -INFINITY;
                if (j + 16 >= ne) s2 = -INFINITY;
                if (j + 24 >= ne) s3 = -INFINITY;
                const float mn = fmaxf(fmaxf(m, s0), fmaxf(fmaxf(s1, s2), s3));
                const float sc = expf(m - mn);
                const float w0 = expf(s0 - mn), w1 = expf(s1 - mn);
                const float w2 = expf(s2 - mn), w3 = expf(s3 - mn);
                den = den * sc + ((w0 + w1) + (w2 + w3));
                #pragma unroll
                for (int i = 0; i < 8; ++i) {
                    float tacc = w0 * x0[i];
                    tacc = fmaf(w1, x1[i], tacc);
                    tacc = fmaf(w2, x2[i], tacc);
                    tacc = fmaf(w3, x3[i], tacc);
                    racc[i] = fmaf(racc[i], sc, tacc);
                }
                m = mn;
                if (!more) break;
                j = jn;
                v0 = n0v; v1 = n1v; v2 = n2v; v3 = n3v;
            }
        }
    } else {
        int j = ns + ggrp;
        if (j < ne) {
            const size_t off = 8 * l16;
            float4 va[4], vb[4];
            {
                const int j1 = j + 8  < ne ? j + 8  : j;
                const int j2 = j + 16 < ne ? j + 16 : j;
                const int j3 = j + 24 < ne ? j + 24 : j;
                const float4* p0 = (const float4*)(x + (size_t)j  * DIM + off);
                const float4* p1 = (const float4*)(x + (size_t)j1 * DIM + off);
                const float4* p2 = (const float4*)(x + (size_t)j2 * DIM + off);
                const float4* p3 = (const float4*)(x + (size_t)j3 * DIM + off);
                va[0] = p0[0]; vb[0] = p0[1];
                va[1] = p1[0]; vb[1] = p1[1];
                va[2] = p2[0]; vb[2] = p2[1];
                va[3] = p3[0]; vb[3] = p3[1];
            }
            while (true) {
                const int jn = j + 32;
                const bool more = (jn < ne);
                float4 na[4], nb[4];
                if (more) {   // depth-2 prefetch (was missing on this path)
                    const int k1 = jn + 8  < ne ? jn + 8  : jn;
                    const int k2 = jn + 16 < ne ? jn + 16 : jn;
                    const int k3 = jn + 24 < ne ? jn + 24 : jn;
                    const float4* p0 = (const float4*)(x + (size_t)jn * DIM + off);
                    const float4* p1 = (const float4*)(x + (size_t)k1 * DIM + off);
                    const float4* p2 = (const float4*)(x + (size_t)k2 * DIM + off);
                    const float4* p3 = (const float4*)(x + (size_t)k3 * DIM + off);
                    na[0] = p0[0]; nb[0] = p0[1];
                    na[1] = p1[0]; nb[1] = p1[1];
                    na[2] = p2[0]; nb[2] = p2[1];
                    na[3] = p3[0]; nb[3] = p3[1];
                }
                float xv[4][8];
                #pragma unroll
                for (int r4 = 0; r4 < 4; ++r4) {
                    xv[r4][0] = va[r4].x; xv[r4][1] = va[r4].y;
                    xv[r4][2] = va[r4].z; xv[r4][3] = va[r4].w;
                    xv[r4][4] = vb[r4].x; xv[r4][5] = vb[r4].y;
                    xv[r4][6] = vb[r4].z; xv[r4][7] = vb[r4].w;
                }
                if (write_bf) {
                    const int jr[4] = {j, j + 8, j + 16, j + 24};
                    #pragma unroll
                    for (int r4 = 0; r4 < 4; ++r4) {
                        if (r4 == 0 || jr[r4] < ne) {
                            int4 pk;
                            unsigned* pu = (unsigned*)&pk;
                            #pragma unroll
                            for (int i = 0; i < 4; ++i)
                                pu[i] = (unsigned)f2bf_u(xv[r4][2 * i])
                                      | ((unsigned)f2bf_u(xv[r4][2 * i + 1]) << 16);
                            *(int4*)(xbf + (size_t)jr[r4] * DIM + off) = pk;
                        }
                    }
                }
                float s0 = 0.f, s1 = 0.f, s2 = 0.f, s3 = 0.f;
                #pragma unroll
                for (int i = 0; i < 8; ++i) {
                    s0 = fmaf(xv[0][i], hreg[i], s0);
                    s1 = fmaf(xv[1][i], hreg[i], s1);
                    s2 = fmaf(xv[2][i], hreg[i], s2);
                    s3 = fmaf(xv[3][i], hreg[i], s3);
                }
                REDUCE16(s0); REDUCE16(s1); REDUCE16(s2); REDUCE16(s3);
                if (j + 8  >= ne) s1 = -INFINITY;
                if (j + 16 >= ne) s2 = -INFINITY;
                if (j + 24 >= ne) s3 = -INFINITY;
                const float mn = fmaxf(fmaxf(m, s0), fmaxf(fmaxf(s1, s2), s3));
                const float sc = expf(m - mn);
                const float w0 = expf(s0 - mn), w1 = expf(s1 - mn);
                const float w2 = expf(s2 - mn), w3 = expf(s3 - mn);
                den = den * sc + ((w0 + w1) + (w2 + w3));
                #pragma unroll
                for (int i = 0; i < 8; ++i) {
                    float tacc = w0 * xv[0][i];
                    tacc = fmaf(w1, xv[1][i], tacc);
                    tacc = fmaf(w2, xv[2][i], tacc);
                    tacc = fmaf(w3, xv[3][i], tacc);
                    racc[i] = fmaf(racc[i], sc, tacc);
                }
                m = mn;
                if (!more) break;
                j = jn;
                #pragma unroll
                for (int r4 = 0; r4 < 4; ++r4) { va[r4] = na[r4]; vb[r4] = nb[r4]; }
            }
        }
    }

    // ---- merge 8 group states
    if (l16 == 0) { gm[ggrp] = m; gden[ggrp] = den; }
    *(float4*)&racc_s[ggrp][8 * l16]     = make_float4(racc[0], racc[1], racc[2], racc[3]);
    *(float4*)&racc_s[ggrp][8 * l16 + 4] = make_float4(racc[4], racc[5], racc[6], racc[7]);
    __syncthreads();

    {
        float mM = gm[0];
        #pragma unroll
        for (int g = 1; g < 8; ++g) mM = fmaxf(mM, gm[g]);
        float dtot = 0.f, rtot = 0.f;
        #pragma unroll
        for (int g = 0; g < 8; ++g) {
            const float k = expf(gm[g] - mM);   // -inf group -> 0
            dtot = fmaf(k, gden[g], dtot);
            rtot = fmaf(k, racc_s[g][tid], rtot);
        }
        const float rv = rtot / (dtot + 1e-16f);
        qstar[(size_t)b * 256 + DIM + tid] = rv;
        abuf[(size_t)b * 384 + 128 + tid] = __float2bfloat16(rv);
    }
}

// ---------------------------------------------------------------------------
extern "C" void kernel_launch(void* const* d_in, const int* in_sizes, int n_in,
                              void* d_out, int out_size, void* d_ws, size_t ws_size,
                              hipStream_t stream) {
    const float* x     = (const float*)d_in[0];
    const int*   batch = (const int*)d_in[1];
    const float* Wih   = (const float*)d_in[2];
    const float* Whh   = (const float*)d_in[3];
    const float* bih   = (const float*)d_in[4];
    const float* bhh   = (const float*)d_in[5];
    float* out = (float*)d_out;

    // workspace layout (cbuf ping-pong)
    float* cbufA = (float*)d_ws;                            // 8192*128 f32
    float* cbufB = cbufA + (size_t)NSEG * DIM;              // 8192*128 f32
    float* gates = cbufB + (size_t)NSEG * DIM;              // 8192*512 f32
    __hip_bfloat16* abuf = (__hip_bfloat16*)(gates + (size_t)NSEG * 512);  // 8192*384
    __hip_bfloat16* wbuf = abuf + (size_t)NSEG * 384;       // 512*384
    int* seg = (int*)(wbuf + (size_t)512 * 384);
    size_t fixed_bytes = (size_t)((char*)(seg + NSEG + 1) - (char*)d_ws);
    size_t xbf_off = (fixed_bytes + 15) & ~(size_t)15;
    ushort_t* xbf = (ushort_t*)((char*)d_ws + xbf_off);
    size_t need = xbf_off + (size_t)NNODES * DIM * sizeof(ushort_t);
    const int use_xbf = (ws_size >= need) ? 1 : 0;

    setup_k<<<(512 * 384) / 256, 256, 0, stream>>>(Wih, Whh, wbuf, batch, seg);

    float* cpp[2] = {cbufA, cbufB};
    dim3 ggrid(512 / 128, NSEG / 128);   // (4, 64)
    for (int t = 0; t < TSTEPS; ++t) {
        if (t > 0)
            gemm_mfma_k<<<ggrid, 256, 0, stream>>>(abuf, wbuf, gates);
        const int read_bf  = (use_xbf && t > 0) ? 1 : 0;
        const int write_bf = (use_xbf && t == 0) ? 1 : 0;
        const float* cin = cpp[(t + 1) & 1];
        float*       cot = cpp[t & 1];
        attn_lstm_k<<<NSEG, 128, 0, stream>>>(x, xbf, seg, gates, bih, bhh,
                                              cin, cot, out, abuf,
                                              (t == 0) ? 1 : 0, read_bf, write_bf);
    }
}